// Round 9
// baseline (471.195 us; speedup 1.0000x reference)
//
#include <hip/hip_runtime.h>
#include <hip/hip_fp16.h>
#include <math.h>

// RPMNet registration, fused persistent kernel, linear-domain Sinkhorn with
// REGISTER-RESIDENT fp16 K. B=16, N=1024, feat 6; 3 reg iters x 5 sk iters.
// R15: DUAL-BATCH SOFTWARE PIPELINE. Each block owns 32 rows of batch A
// (=2p) AND 32 rows of batch B (=2p+1); 8 pairs x 32 blocks = 256 blocks =
// 1 block/CU. Per sk phase: compute A -> atomics A -> bump A EARLY ->
// compute B (A's barrier round trip + other blocks' arrivals hide under
// this ~2.5us) -> atomics B -> bump B -> spin A (already done) -> spin B
// -> coop-reload both. The per-phase MALL sync chain (~12us of the measured
// 14.8us/phase; R12-R14 established compute is only ~2.5us) is thus hidden
// under the partner batch's compute instead of idling the CU. K register
// budget UNCHANGED (4 rows/lane x 2 batches = 64 VGPRs). Reduce width per
// batch back to 32 blocks (R0<->R1 proved width-invariance). Barrier = the
// R12-proven relaxed agent-scope spin, split into bump/spin halves; all
// cross-wave drains ride the compiler's full s_waitcnt-before-s_barrier.
//
// ws (floats): [0..767] accum[3][16][16] | [1024..1535 as u32] barriers
//              | [1536..] Sv[15][16][1024]   (all prep-zeroed each launch)

#define BATCH 16
#define NPTS  1024
#define REG_ITERS 3
#define SK_ITERS  5
#define EPS 1e-5f
#define LOG2E 1.44269504088896f

#define BLOCK_T   512
#define BLK_PER_B 32          // blocks participating in each batch's barrier
#define NWAVES    8
#define NROW      4           // rows per lane per batch

#define WS_ACC  0
#define WS_BARU 1024
#define WS_SV   1536
#define SV_STRIDE (BATCH * NPTS)
#define PREP_FLOATS (WS_SV + REG_ITERS * SK_ITERS * SV_STRIDE)  // 247296 = 966*256

__device__ __forceinline__ float ld_coh(const float* p) {
    return __hip_atomic_load((float*)p, __ATOMIC_RELAXED, __HIP_MEMORY_SCOPE_AGENT);
}
__device__ __forceinline__ float2 ld_coh2(const float* p) {
    unsigned long long u = __hip_atomic_load((const unsigned long long*)p,
                                             __ATOMIC_RELAXED, __HIP_MEMORY_SCOPE_AGENT);
    union { unsigned long long u; float2 f; } c; c.u = u; return c.f;
}
__device__ __forceinline__ void add_coh(float* p, float v) {
    __hip_atomic_fetch_add(p, v, __ATOMIC_RELAXED, __HIP_MEMORY_SCOPE_AGENT);
}
__device__ __forceinline__ void bump_coh(unsigned* c) {
    __hip_atomic_fetch_add(c, 1u, __ATOMIC_RELAXED, __HIP_MEMORY_SCOPE_AGENT);
}
__device__ __forceinline__ void spin_coh(unsigned* c, unsigned t) {
    while (__hip_atomic_load(c, __ATOMIC_RELAXED, __HIP_MEMORY_SCOPE_AGENT) < t)
        __builtin_amdgcn_s_sleep(1);
}

// u-pass for batch S: row sums (sk==0) or K@wv using wvS[S]; -> OUTWU[0..3]
#define UPASS(S, OUTWU)                                                       \
    {                                                                         \
        float Su[NROW];                                                       \
        _Pragma("unroll") for (int r = 0; r < NROW; ++r) Su[r] = 0.f;         \
        if (sk == 0) {                                                        \
            _Pragma("unroll") for (int j = 0; j < 8; ++j)                     \
            _Pragma("unroll") for (int r = 0; r < NROW; ++r) {                \
                float2 kk = __half22float2(Kh[S][r][j]);                      \
                Su[r] += kk.x + kk.y;                                         \
            }                                                                 \
        } else {                                                              \
            float wv0[8], wv1[8];                                             \
            _Pragma("unroll") for (int j = 0; j < 8; ++j) {                   \
                wv0[j] = wvS[S][2*lane + 128*j];                              \
                wv1[j] = wvS[S][2*lane + 128*j + 1];                          \
            }                                                                 \
            _Pragma("unroll") for (int j = 0; j < 8; ++j)                     \
            _Pragma("unroll") for (int r = 0; r < NROW; ++r) {                \
                float2 kk = __half22float2(Kh[S][r][j]);                      \
                Su[r] = fmaf(kk.x, wv0[j], fmaf(kk.y, wv1[j], Su[r]));        \
            }                                                                 \
        }                                                                     \
        _Pragma("unroll") for (int r = 0; r < NROW; ++r) {                    \
            float a = Su[r];                                                  \
            for (int off = 32; off; off >>= 1) a += __shfl_down(a, off);      \
            OUTWU[r] = __builtin_amdgcn_rcpf(1.f + __shfl(a, 0));             \
        }                                                                     \
    }

// v-pass for batch S: per-wave column partials into svp
#define VPASS(S)                                                              \
    _Pragma("unroll") for (int j = 0; j < 8; ++j) {                           \
        float p0 = 0.f, p1 = 0.f;                                             \
        _Pragma("unroll") for (int r = 0; r < NROW; ++r) {                    \
            float2 kk = __half22float2(Kh[S][r][j]);                          \
            p0 = fmaf(kk.x, wu[S][r], p0);                                    \
            p1 = fmaf(kk.y, wu[S][r], p1);                                    \
        }                                                                     \
        svp[wid][2*lane + 128*j]     = p0;                                    \
        svp[wid][2*lane + 128*j + 1] = p1;                                    \
    }

// cross-wave column reduce -> one agent atomic per column
#define COLRED(vb)                                                            \
    _Pragma("unroll") for (int cc = 0; cc < 2; ++cc) {                        \
        int c = tid + BLOCK_T*cc;                                             \
        float sgm = svp[0][c]+svp[1][c]+svp[2][c]+svp[3][c]                   \
                  + svp[4][c]+svp[5][c]+svp[6][c]+svp[7][c];                  \
        add_coh((vb) + c, sgm);                                               \
    }

// K-build for batch S
#define KBUILD(S, GROW, BET2, ALP, TB2)                                       \
    {                                                                         \
        float rx[NROW],ry[NROW],rz[NROW],f3[NROW],f4[NROW],f5[NROW],cr[NROW]; \
        _Pragma("unroll") for (int r = 0; r < NROW; ++r) {                    \
            const float* pp = psrc + (size_t)((GROW) + r) * 6;                \
            float x = pp[0], y = pp[1], z = pp[2];                            \
            float tx = tT[S][0]*x + tT[S][1]*y + tT[S][2]*z  + tT[S][3];      \
            float ty = tT[S][4]*x + tT[S][5]*y + tT[S][6]*z  + tT[S][7];      \
            float tz = tT[S][8]*x + tT[S][9]*y + tT[S][10]*z + tT[S][11];     \
            f3[r]=pp[3]; f4[r]=pp[4]; f5[r]=pp[5];                            \
            rx[r]=tx; ry[r]=ty; rz[r]=tz;                                     \
            float sq = tx*tx+ty*ty+tz*tz+f3[r]*f3[r]+f4[r]*f4[r]+f5[r]*f5[r]; \
            cr[r] = (BET2) * ((ALP) - sq);                                    \
        }                                                                     \
        _Pragma("unroll") for (int j = 0; j < 8; ++j) {                       \
            const float* L0 = &refL[S][(2*lane + 128*j) * 7];                 \
            const float* L1 = L0 + 7;                                         \
            float a0=L0[0],a1=L0[1],a2=L0[2],a3=L0[3],a4=L0[4],a5=L0[5];      \
            float c0=L1[0],c1=L1[1],c2=L1[2],c3=L1[3],c4=L1[4],c5=L1[5];      \
            float tk0=(BET2)*L0[6], tk1=(BET2)*L1[6];                         \
            _Pragma("unroll") for (int r = 0; r < NROW; ++r) {                \
                float d0 = rx[r]*a0+ry[r]*a1+rz[r]*a2+f3[r]*a3+f4[r]*a4+f5[r]*a5; \
                float d1 = rx[r]*c0+ry[r]*c1+rz[r]*c2+f3[r]*c3+f4[r]*c4+f5[r]*c5; \
                float k0 = __builtin_amdgcn_exp2f(fmaf((TB2), d0, cr[r]-tk0));\
                float k1 = __builtin_amdgcn_exp2f(fmaf((TB2), d1, cr[r]-tk1));\
                Kh[S][r][j] = __floats2half2_rn(k0, k1);                      \
            }                                                                 \
        }                                                                     \
    }

// moments + (last-iter) perm for batch S; ends with accum atomics by tid<16
#define MOMENTS(S, GROW, ACPTR)                                               \
    {                                                                         \
        float wv0[8], wv1[8];                                                 \
        _Pragma("unroll") for (int j = 0; j < 8; ++j) {                       \
            wv0[j] = wvS[S][2*lane + 128*j];                                  \
            wv1[j] = wvS[S][2*lane + 128*j + 1];                              \
        }                                                                     \
        float rx[NROW], ry[NROW], rz[NROW];                                   \
        _Pragma("unroll") for (int r = 0; r < NROW; ++r) {                    \
            const float* pp = psrc + (size_t)((GROW) + r) * 6;                \
            float x = pp[0], y = pp[1], z = pp[2];                            \
            rx[r] = tT[S][0]*x + tT[S][1]*y + tT[S][2]*z  + tT[S][3];         \
            ry[r] = tT[S][4]*x + tT[S][5]*y + tT[S][6]*z  + tT[S][7];         \
            rz[r] = tT[S][8]*x + tT[S][9]*y + tT[S][10]*z + tT[S][11];        \
        }                                                                     \
        float pS[16];                                                         \
        _Pragma("unroll") for (int i2 = 0; i2 < 16; ++i2) pS[i2] = 0.f;       \
        for (int r = 0; r < NROW; ++r) {                                      \
            float s2=0.f, smx=0.f, smy=0.f, smz=0.f;                          \
            const float w = wu[S][r];                                         \
            _Pragma("unroll") for (int j = 0; j < 8; ++j) {                   \
                int k0 = 2*lane + 128*j;                                      \
                float2 kk = __half22float2(Kh[S][r][j]);                      \
                float p0 = kk.x * w * wv0[j];                                 \
                float p1 = kk.y * w * wv1[j];                                 \
                const float* L0 = &refL[S][k0 * 7];                           \
                const float* L1 = L0 + 7;                                     \
                s2  += p0 + p1;                                               \
                smx += p0*L0[0] + p1*L1[0];                                   \
                smy += p0*L0[1] + p1*L1[1];                                   \
                smz += p0*L0[2] + p1*L1[2];                                   \
                if (last) {                                                   \
                    __builtin_nontemporal_store(p0, &perm[(size_t)((GROW)+r)*NPTS + k0]);     \
                    __builtin_nontemporal_store(p1, &perm[(size_t)((GROW)+r)*NPTS + k0 + 1]); \
                }                                                             \
            }                                                                 \
            for (int off = 32; off; off >>= 1) {                              \
                s2  += __shfl_down(s2,  off);                                 \
                smx += __shfl_down(smx, off);                                 \
                smy += __shfl_down(smy, off);                                 \
                smz += __shfl_down(smz, off);                                 \
            }                                                                 \
            if (lane == 0) {                                                  \
                float inv = 1.f / (s2 + EPS);                                 \
                float bx = smx*inv, by = smy*inv, bz = smz*inv;               \
                float fx = rx[r], fy = ry[r], fz = rz[r];                     \
                pS[0] += s2;                                                  \
                pS[1] += s2*fx;  pS[2] += s2*fy;  pS[3] += s2*fz;             \
                pS[4] += s2*bx;  pS[5] += s2*by;  pS[6] += s2*bz;             \
                pS[7] += s2*fx*bx;  pS[8]  += s2*fx*by;  pS[9]  += s2*fx*bz;  \
                pS[10]+= s2*fy*bx;  pS[11] += s2*fy*by;  pS[12] += s2*fy*bz;  \
                pS[13]+= s2*fz*bx;  pS[14] += s2*fz*by;  pS[15] += s2*fz*bz;  \
            }                                                                 \
        }                                                                     \
        if (lane == 0) {                                                      \
            _Pragma("unroll") for (int i2 = 0; i2 < 16; ++i2)                 \
                sred[wid][i2] = pS[i2];                                       \
        }                                                                     \
        __syncthreads();                                                      \
        if (tid < 16) {                                                       \
            float s3 = sred[0][tid]+sred[1][tid]+sred[2][tid]+sred[3][tid]    \
                     + sred[4][tid]+sred[5][tid]+sred[6][tid]+sred[7][tid];   \
            add_coh((ACPTR) + tid, s3);                                       \
        }                                                                     \
    }

// weighted Kabsch from 16 accum moments + old T -> new T (12 floats)
__device__ void kabsch_svd(const float* ac, const float* Told, float* Tnew) {
    double Sw = ac[0];
    double Sa[3] = {ac[1], ac[2], ac[3]};
    double Sb[3] = {ac[4], ac[5], ac[6]};
    double D  = Sw + (double)EPS;
    double ca0 = Sa[0]/D, ca1 = Sa[1]/D, ca2 = Sa[2]/D;
    double cb0 = Sb[0]/D, cb1 = Sb[1]/D, cb2 = Sb[2]/D;
    double f  = (2.0 - Sw / D) / D;
    double Am[3][3];
    for (int m = 0; m < 3; ++m)
        for (int n = 0; n < 3; ++n)
            Am[m][n] = (double)ac[7 + m*3 + n] - f * Sa[m] * Sb[n];
    double S[3][3];
    for (int i = 0; i < 3; ++i)
        for (int j = 0; j < 3; ++j) {
            double a2 = 0;
            for (int m = 0; m < 3; ++m) a2 += Am[m][i] * Am[m][j];
            S[i][j] = a2;
        }
    double V[3][3] = {{1,0,0},{0,1,0},{0,0,1}};
    const int prr[3] = {0,0,1}, qrr[3] = {1,2,2};
    for (int sweep = 0; sweep < 25; ++sweep) {
        double off = S[0][1]*S[0][1] + S[0][2]*S[0][2] + S[1][2]*S[1][2];
        if (off < 1e-28) break;
        for (int pi = 0; pi < 3; ++pi) {
            int p = prr[pi], q = qrr[pi];
            double apq = S[p][q];
            if (fabs(apq) < 1e-300) continue;
            double theta = (S[q][q] - S[p][p]) / (2.0 * apq);
            double tt = ((theta >= 0) ? 1.0 : -1.0) / (fabs(theta) + sqrt(theta*theta + 1.0));
            double cth = 1.0 / sqrt(tt*tt + 1.0), sth = tt * cth;
            for (int m = 0; m < 3; ++m) { double a1=S[m][p], a2=S[m][q]; S[m][p]=cth*a1-sth*a2; S[m][q]=sth*a1+cth*a2; }
            for (int m = 0; m < 3; ++m) { double a1=S[p][m], a2=S[q][m]; S[p][m]=cth*a1-sth*a2; S[q][m]=sth*a1+cth*a2; }
            for (int m = 0; m < 3; ++m) { double a1=V[m][p], a2=V[m][q]; V[m][p]=cth*a1-sth*a2; V[m][q]=sth*a1+cth*a2; }
        }
    }
    double lam[3] = {S[0][0], S[1][1], S[2][2]};
    int idx[3] = {0,1,2};
    if (lam[idx[0]] < lam[idx[1]]) { int t2=idx[0]; idx[0]=idx[1]; idx[1]=t2; }
    if (lam[idx[0]] < lam[idx[2]]) { int t2=idx[0]; idx[0]=idx[2]; idx[2]=t2; }
    if (lam[idx[1]] < lam[idx[2]]) { int t2=idx[1]; idx[1]=idx[2]; idx[2]=t2; }
    double Vs[3][3], sv[3];
    for (int i = 0; i < 3; ++i) {
        int c = idx[i];
        for (int m = 0; m < 3; ++m) Vs[m][i] = V[m][c];
        double l = lam[c]; sv[i] = sqrt(l > 0 ? l : 0);
    }
    double Us[3][3] = {{1,0,0},{0,1,0},{0,0,1}};
    double smax = sv[0] > 1e-300 ? sv[0] : 1e-300;
    for (int i = 0; i < 3; ++i) {
        double ux = Am[0][0]*Vs[0][i] + Am[0][1]*Vs[1][i] + Am[0][2]*Vs[2][i];
        double uy = Am[1][0]*Vs[0][i] + Am[1][1]*Vs[1][i] + Am[1][2]*Vs[2][i];
        double uz = Am[2][0]*Vs[0][i] + Am[2][1]*Vs[1][i] + Am[2][2]*Vs[2][i];
        if (sv[i] > 1e-12 * smax) {
            Us[0][i] = ux/sv[i]; Us[1][i] = uy/sv[i]; Us[2][i] = uz/sv[i];
        } else if (i == 2) {
            double cx = Us[1][0]*Us[2][1] - Us[2][0]*Us[1][1];
            double cy = Us[2][0]*Us[0][1] - Us[0][0]*Us[2][1];
            double cz = Us[0][0]*Us[1][1] - Us[1][0]*Us[0][1];
            double n = sqrt(cx*cx + cy*cy + cz*cz); n = n > 1e-300 ? n : 1.0;
            Us[0][i] = cx/n; Us[1][i] = cy/n; Us[2][i] = cz/n;
        }
    }
    double M[3][3];
    for (int m = 0; m < 3; ++m)
        for (int n = 0; n < 3; ++n)
            M[m][n] = Vs[m][0]*Us[n][0] + Vs[m][1]*Us[n][1] + Vs[m][2]*Us[n][2];
    double det = M[0][0]*(M[1][1]*M[2][2]-M[1][2]*M[2][1])
               - M[0][1]*(M[1][0]*M[2][2]-M[1][2]*M[2][0])
               + M[0][2]*(M[1][0]*M[2][1]-M[1][1]*M[2][0]);
    double g3 = (det > 0.0) ? 1.0 : -1.0;
    double R[3][3];
    for (int m = 0; m < 3; ++m)
        for (int n = 0; n < 3; ++n)
            R[m][n] = Vs[m][0]*Us[n][0] + Vs[m][1]*Us[n][1] + g3*Vs[m][2]*Us[n][2];
    double ti[3];
    ti[0] = -(R[0][0]*ca0 + R[0][1]*ca1 + R[0][2]*ca2) + cb0;
    ti[1] = -(R[1][0]*ca0 + R[1][1]*ca1 + R[1][2]*ca2) + cb1;
    ti[2] = -(R[2][0]*ca0 + R[2][1]*ca1 + R[2][2]*ca2) + cb2;
    double Ro[3][3] = {{Told[0],Told[1],Told[2]},{Told[4],Told[5],Told[6]},{Told[8],Told[9],Told[10]}};
    double to[3] = {Told[3], Told[7], Told[11]};
    for (int m = 0; m < 3; ++m) {
        for (int n = 0; n < 3; ++n)
            Tnew[m*4+n] = (float)(R[m][0]*Ro[0][n] + R[m][1]*Ro[1][n] + R[m][2]*Ro[2][n]);
        Tnew[m*4+3] = (float)(R[m][0]*to[0] + R[m][1]*to[1] + R[m][2]*to[2] + ti[m]);
    }
}

__global__ __launch_bounds__(256) void prep_kernel(float* ws) {
    int i = blockIdx.x * 256 + threadIdx.x;   // grid 966 x 256
    ws[i] = 0.f;
}

__global__
__attribute__((amdgpu_flat_work_group_size(BLOCK_T, BLOCK_T), amdgpu_waves_per_eu(2, 2)))
void rpm_kernel(
        const float* __restrict__ psrc, const float* __restrict__ pref,
        const float* __restrict__ beta, const float* __restrict__ alpha,
        float* __restrict__ ws, float* __restrict__ outT, float* __restrict__ perm)
{
    __shared__ float refL[2][NPTS * 7];       // 56 KB: both batches' features
    __shared__ float svp[NWAVES][NPTS];       // 32 KB: per-wave column partials
    __shared__ float wvS[2][NPTS];            // 8 KB: both batches' wv
    __shared__ float sred[NWAVES][16];
    __shared__ float tT[2][12];
    __shared__ float tTn[2][12];

    const int blk = blockIdx.x, p = blk & 7, sub = blk >> 3;    // 8 pairs x 32
    const int bA = 2*p, bB = 2*p + 1;
    const int tid = threadIdx.x, wid = tid >> 6, lane = tid & 63;
    const int rbase = (sub << 5) + (wid << 2);                  // 32 rows/block/batch
    const int growA = (bA << 10) + rbase;
    const int growB = (bB << 10) + rbase;

    float*    accA_ = ws + WS_ACC;
    unsigned* barA_ = (unsigned*)ws + WS_BARU + bA * 32;
    unsigned* barB_ = (unsigned*)ws + WS_BARU + bB * 32;
    float*    svA   = ws + WS_SV;
    unsigned  phase = 0;

    const float bet2A = beta[bA] * LOG2E, alpA = alpha[bA], tb2A = 2.f * bet2A;
    const float bet2B = beta[bB] * LOG2E, alpB = alpha[bB], tb2B = 2.f * bet2B;

    // ---- stage both batches' ref features to LDS
    for (int i = tid; i < NPTS; i += BLOCK_T) {
        #pragma unroll
        for (int s = 0; s < 2; ++s) {
            const float* pr = pref + ((size_t)((s ? bB : bA) << 10) + i) * 6;
            float x=pr[0], y=pr[1], z=pr[2], aa=pr[3], bb=pr[4], cc=pr[5];
            float* o = &refL[s][i * 7];
            o[0]=x; o[1]=y; o[2]=z; o[3]=aa; o[4]=bb; o[5]=cc;
            o[6] = x*x + y*y + z*z + aa*aa + bb*bb + cc*cc;
        }
    }
    if (tid < 12) {
        float v = (tid == 0 || tid == 5 || tid == 10) ? 1.f : 0.f;
        tT[0][tid] = v; tT[1][tid] = v;
    }
    __syncthreads();

    __half2 Kh[2][NROW][8];   // 64 VGPRs total (same as single-batch R12)
    float wu[2][NROW];

    for (int it = 0; it < REG_ITERS; ++it) {
        const bool last = (it == REG_ITERS - 1);

        KBUILD(0, growA, bet2A, alpA, tb2A);
        KBUILD(1, growB, bet2B, alpB, tb2B);

        for (int sk = 0; sk < SK_ITERS; ++sk) {
            float* vbA_ = svA + (size_t)(it*SK_ITERS + sk) * SV_STRIDE + (bA << 10);
            float* vbB_ = svA + (size_t)(it*SK_ITERS + sk) * SV_STRIDE + (bB << 10);

            // ---- A sub-phase
            UPASS(0, wu[0]);
            VPASS(0);
            __syncthreads();                    // svp_A complete
            COLRED(vbA_);
            // ---- B u-pass overlaps A's atomic flight (no svp touch)
            UPASS(1, wu[1]);
            __syncthreads();                    // svp_A reads done; A atomics drained
            if (tid == 0) bump_coh(barA_);      // A barrier round trip hides under B
            // ---- B sub-phase
            VPASS(1);
            __syncthreads();                    // svp_B complete
            COLRED(vbB_);
            __syncthreads();                    // B atomics drained
            ++phase;
            if (tid == 0) {
                bump_coh(barB_);
                spin_coh(barA_, BLK_PER_B * phase);   // usually already done
                spin_coh(barB_, BLK_PER_B * phase);
            }
            __syncthreads();
            // ---- coop reload both slices -> wvS
            {
                float2 g = ld_coh2(vbA_ + 2*tid);
                wvS[0][2*tid]     = __builtin_amdgcn_rcpf(1.f + g.x);
                wvS[0][2*tid + 1] = __builtin_amdgcn_rcpf(1.f + g.y);
                float2 h = ld_coh2(vbB_ + 2*tid);
                wvS[1][2*tid]     = __builtin_amdgcn_rcpf(1.f + h.x);
                wvS[1][2*tid + 1] = __builtin_amdgcn_rcpf(1.f + h.y);
            }
            __syncthreads();
        }

        // ---- C phase: moments/perm for A, then B, pipelined the same way
        float* acA_ = accA_ + it * 256 + bA * 16;
        float* acB_ = accA_ + it * 256 + bB * 16;

        MOMENTS(0, growA, acA_);
        __syncthreads();                        // A accum atomics drained; sred free
        if (tid == 0) bump_coh(barA_);
        MOMENTS(1, growB, acB_);
        __syncthreads();                        // B accum atomics drained
        ++phase;
        if (tid == 0) {
            bump_coh(barB_);
            spin_coh(barA_, BLK_PER_B * phase);
            spin_coh(barB_, BLK_PER_B * phase);
        }
        __syncthreads();
        // parallel accum readback for both batches
        if (tid < 16)                      sred[0][tid]      = ld_coh(acA_ + tid);
        else if (tid >= 64 && tid < 80)    sred[1][tid - 64] = ld_coh(acB_ + (tid - 64));
        __syncthreads();

        if (!last || sub == 0) {
            // two SVDs in parallel on lane0 of wave0 / wave1
            if (tid == 0) {
                float acl[16], Tl[12];
                #pragma unroll
                for (int i2 = 0; i2 < 16; ++i2) acl[i2] = sred[0][i2];
                #pragma unroll
                for (int i2 = 0; i2 < 12; ++i2) Tl[i2] = tT[0][i2];
                kabsch_svd(acl, Tl, &tTn[0][0]);
            }
            if (tid == 64) {
                float acl[16], Tl[12];
                #pragma unroll
                for (int i2 = 0; i2 < 16; ++i2) acl[i2] = sred[1][i2];
                #pragma unroll
                for (int i2 = 0; i2 < 12; ++i2) Tl[i2] = tT[1][i2];
                kabsch_svd(acl, Tl, &tTn[1][0]);
            }
            __syncthreads();
            if (tid < 12)                    tT[0][tid]      = tTn[0][tid];
            else if (tid >= 64 && tid < 76)  tT[1][tid - 64] = tTn[1][tid - 64];
            __syncthreads();
            if (last && tid == 0) {
                #pragma unroll
                for (int i2 = 0; i2 < 12; ++i2) outT[bA * 12 + i2] = tT[0][i2];
            }
            if (last && tid == 64) {
                #pragma unroll
                for (int i2 = 0; i2 < 12; ++i2) outT[bB * 12 + i2] = tT[1][i2];
            }
        }
    }
}

extern "C" void kernel_launch(void* const* d_in, const int* in_sizes, int n_in,
                              void* d_out, int out_size, void* d_ws, size_t ws_size,
                              hipStream_t stream) {
    const float* psrc  = (const float*)d_in[0];
    const float* pref  = (const float*)d_in[1];
    const float* beta  = (const float*)d_in[2];
    const float* alpha = (const float*)d_in[3];

    float* out     = (float*)d_out;
    float* outT    = out;            // (16,3,4)
    float* outPerm = out + 192;      // (16,1024,1024)
    float* ws      = (float*)d_ws;

    prep_kernel<<<PREP_FLOATS / 256, 256, 0, stream>>>(ws);

    void* args[] = { (void*)&psrc, (void*)&pref, (void*)&beta, (void*)&alpha,
                     (void*)&ws, (void*)&outT, (void*)&outPerm };
    hipError_t ce = hipLaunchCooperativeKernel((const void*)rpm_kernel,
                                               dim3(256), dim3(BLOCK_T),
                                               args, 0, stream);
    if (ce != hipSuccess) {
        rpm_kernel<<<dim3(256), dim3(BLOCK_T), 0, stream>>>(
            psrc, pref, beta, alpha, ws, outT, outPerm);
    }
}

// Round 10
// 354.928 us; speedup vs baseline: 1.3276x; 1.3276x over previous
//
#include <hip/hip_runtime.h>
#include <hip/hip_fp16.h>
#include <math.h>

// RPMNet registration, fused persistent kernel, linear-domain Sinkhorn with
// REGISTER-RESIDENT fp16 K. B=16, N=1024, feat 6; 3 reg iters x 5 sk iters.
// R16: PRIVATE-SLOT COLUMN REDUCE on the R14 skeleton (266us proven).
// R15's dose-response showed per-phase cost tracks MALL atomic RMW fan-in
// (16 blocks x 16 cols/64B-line = 256 serialized RMWs/line/phase; the
// pre-barrier vmcnt(0) drain waits behind them). Now each block STORES its
// 1024-col partial into a private slot (one 8B relaxed agent store/thread,
// no RMW, parallel completion); after the proven spin barrier each block
// sums the 16 slots on the read side (16 independent 8B loads/thread, one
// latency exposure, fixed order -> bit-identical wv across blocks).
// Slots are double-buffered by sk-phase parity (no zeroing; the barrier
// chain guarantees no overwrite race). C-phase Sv reload deleted (wvS
// already holds sk=4's data). Accum keeps the R12 atomic path (3 phases).
//
// ws: [0..767] accum floats | [1024..1535 as u32] barriers
//     | u64[2][16][16][512] Sv slots at float offset 1536 (byte 6144)
//     prep zeroes only the first 1536 floats; slots need no zeroing.
//     Workspace required: ~2.11 MB (R13 proved >=1.93 MB available).

#define BATCH 16
#define NPTS  1024
#define REG_ITERS 3
#define SK_ITERS  5
#define EPS 1e-5f
#define LOG2E 1.44269504088896f

#define BLOCK_T   512
#define BLK_PER_B 16          // blocks per batch
#define NWAVES    8           // waves per block

#define WS_ACC  0
#define WS_BARU 1024
#define WS_SVU  768           // u64 index of slot region (float index 1536)
#define SLOT_U  512           // u64 per slot (1024 floats)
#define PREP_FLOATS 1536      // accum + barriers only; grid 6 x 256

__device__ __forceinline__ float ld_coh(const float* p) {
    return __hip_atomic_load((float*)p, __ATOMIC_RELAXED, __HIP_MEMORY_SCOPE_AGENT);
}
__device__ __forceinline__ unsigned long long ld_coh64(const unsigned long long* p) {
    return __hip_atomic_load((unsigned long long*)p, __ATOMIC_RELAXED,
                             __HIP_MEMORY_SCOPE_AGENT);
}
__device__ __forceinline__ void st_coh64(unsigned long long* p, unsigned long long v) {
    __hip_atomic_store(p, v, __ATOMIC_RELAXED, __HIP_MEMORY_SCOPE_AGENT);
}
__device__ __forceinline__ void add_coh(float* p, float v) {
    __hip_atomic_fetch_add(p, v, __ATOMIC_RELAXED, __HIP_MEMORY_SCOPE_AGENT);
}

// relaxed spin barrier (R12-proven). The leading __syncthreads makes every
// wave drain its own vmem (stores complete at the MALL) before tid0 bumps.
__device__ __forceinline__ void batch_barrier(unsigned* bar, unsigned target) {
    __syncthreads();
    if (threadIdx.x == 0) {
        __builtin_amdgcn_s_waitcnt(0);
        __hip_atomic_fetch_add(bar, 1u, __ATOMIC_RELAXED, __HIP_MEMORY_SCOPE_AGENT);
        while (__hip_atomic_load(bar, __ATOMIC_RELAXED, __HIP_MEMORY_SCOPE_AGENT) < target)
            __builtin_amdgcn_s_sleep(1);
    }
    __syncthreads();
    __asm__ __volatile__("" ::: "memory");
}

// weighted Kabsch from 16 accum moments + old T -> new T (12 floats)
__device__ void kabsch_svd(const float* ac, const float* Told, float* Tnew) {
    double Sw = ac[0];
    double Sa[3] = {ac[1], ac[2], ac[3]};
    double Sb[3] = {ac[4], ac[5], ac[6]};
    double D  = Sw + (double)EPS;
    double ca0 = Sa[0]/D, ca1 = Sa[1]/D, ca2 = Sa[2]/D;
    double cb0 = Sb[0]/D, cb1 = Sb[1]/D, cb2 = Sb[2]/D;
    double f  = (2.0 - Sw / D) / D;
    double Am[3][3];
    for (int m = 0; m < 3; ++m)
        for (int n = 0; n < 3; ++n)
            Am[m][n] = (double)ac[7 + m*3 + n] - f * Sa[m] * Sb[n];
    double S[3][3];
    for (int i = 0; i < 3; ++i)
        for (int j = 0; j < 3; ++j) {
            double a2 = 0;
            for (int m = 0; m < 3; ++m) a2 += Am[m][i] * Am[m][j];
            S[i][j] = a2;
        }
    double V[3][3] = {{1,0,0},{0,1,0},{0,0,1}};
    const int prr[3] = {0,0,1}, qrr[3] = {1,2,2};
    for (int sweep = 0; sweep < 25; ++sweep) {
        double off = S[0][1]*S[0][1] + S[0][2]*S[0][2] + S[1][2]*S[1][2];
        if (off < 1e-28) break;
        for (int pi = 0; pi < 3; ++pi) {
            int p = prr[pi], q = qrr[pi];
            double apq = S[p][q];
            if (fabs(apq) < 1e-300) continue;
            double theta = (S[q][q] - S[p][p]) / (2.0 * apq);
            double tt = ((theta >= 0) ? 1.0 : -1.0) / (fabs(theta) + sqrt(theta*theta + 1.0));
            double cth = 1.0 / sqrt(tt*tt + 1.0), sth = tt * cth;
            for (int m = 0; m < 3; ++m) { double a1=S[m][p], a2=S[m][q]; S[m][p]=cth*a1-sth*a2; S[m][q]=sth*a1+cth*a2; }
            for (int m = 0; m < 3; ++m) { double a1=S[p][m], a2=S[q][m]; S[p][m]=cth*a1-sth*a2; S[q][m]=sth*a1+cth*a2; }
            for (int m = 0; m < 3; ++m) { double a1=V[m][p], a2=V[m][q]; V[m][p]=cth*a1-sth*a2; V[m][q]=sth*a1+cth*a2; }
        }
    }
    double lam[3] = {S[0][0], S[1][1], S[2][2]};
    int idx[3] = {0,1,2};
    if (lam[idx[0]] < lam[idx[1]]) { int t2=idx[0]; idx[0]=idx[1]; idx[1]=t2; }
    if (lam[idx[0]] < lam[idx[2]]) { int t2=idx[0]; idx[0]=idx[2]; idx[2]=t2; }
    if (lam[idx[1]] < lam[idx[2]]) { int t2=idx[1]; idx[1]=idx[2]; idx[2]=t2; }
    double Vs[3][3], sv[3];
    for (int i = 0; i < 3; ++i) {
        int c = idx[i];
        for (int m = 0; m < 3; ++m) Vs[m][i] = V[m][c];
        double l = lam[c]; sv[i] = sqrt(l > 0 ? l : 0);
    }
    double Us[3][3] = {{1,0,0},{0,1,0},{0,0,1}};
    double smax = sv[0] > 1e-300 ? sv[0] : 1e-300;
    for (int i = 0; i < 3; ++i) {
        double ux = Am[0][0]*Vs[0][i] + Am[0][1]*Vs[1][i] + Am[0][2]*Vs[2][i];
        double uy = Am[1][0]*Vs[0][i] + Am[1][1]*Vs[1][i] + Am[1][2]*Vs[2][i];
        double uz = Am[2][0]*Vs[0][i] + Am[2][1]*Vs[1][i] + Am[2][2]*Vs[2][i];
        if (sv[i] > 1e-12 * smax) {
            Us[0][i] = ux/sv[i]; Us[1][i] = uy/sv[i]; Us[2][i] = uz/sv[i];
        } else if (i == 2) {
            double cx = Us[1][0]*Us[2][1] - Us[2][0]*Us[1][1];
            double cy = Us[2][0]*Us[0][1] - Us[0][0]*Us[2][1];
            double cz = Us[0][0]*Us[1][1] - Us[1][0]*Us[0][1];
            double n = sqrt(cx*cx + cy*cy + cz*cz); n = n > 1e-300 ? n : 1.0;
            Us[0][i] = cx/n; Us[1][i] = cy/n; Us[2][i] = cz/n;
        }
    }
    double M[3][3];
    for (int m = 0; m < 3; ++m)
        for (int n = 0; n < 3; ++n)
            M[m][n] = Vs[m][0]*Us[n][0] + Vs[m][1]*Us[n][1] + Vs[m][2]*Us[n][2];
    double det = M[0][0]*(M[1][1]*M[2][2]-M[1][2]*M[2][1])
               - M[0][1]*(M[1][0]*M[2][2]-M[1][2]*M[2][0])
               + M[0][2]*(M[1][0]*M[2][1]-M[1][1]*M[2][0]);
    double g3 = (det > 0.0) ? 1.0 : -1.0;
    double R[3][3];
    for (int m = 0; m < 3; ++m)
        for (int n = 0; n < 3; ++n)
            R[m][n] = Vs[m][0]*Us[n][0] + Vs[m][1]*Us[n][1] + g3*Vs[m][2]*Us[n][2];
    double ti[3];
    ti[0] = -(R[0][0]*ca0 + R[0][1]*ca1 + R[0][2]*ca2) + cb0;
    ti[1] = -(R[1][0]*ca0 + R[1][1]*ca1 + R[1][2]*ca2) + cb1;
    ti[2] = -(R[2][0]*ca0 + R[2][1]*ca1 + R[2][2]*ca2) + cb2;
    double Ro[3][3] = {{Told[0],Told[1],Told[2]},{Told[4],Told[5],Told[6]},{Told[8],Told[9],Told[10]}};
    double to[3] = {Told[3], Told[7], Told[11]};
    for (int m = 0; m < 3; ++m) {
        for (int n = 0; n < 3; ++n)
            Tnew[m*4+n] = (float)(R[m][0]*Ro[0][n] + R[m][1]*Ro[1][n] + R[m][2]*Ro[2][n]);
        Tnew[m*4+3] = (float)(R[m][0]*to[0] + R[m][1]*to[1] + R[m][2]*to[2] + ti[m]);
    }
}

__global__ __launch_bounds__(256) void prep_kernel(float* ws) {
    int i = blockIdx.x * 256 + threadIdx.x;   // grid 6 x 256
    ws[i] = 0.f;
}

__global__
__attribute__((amdgpu_flat_work_group_size(BLOCK_T, BLOCK_T), amdgpu_waves_per_eu(2, 2)))
void rpm_kernel(
        const float* __restrict__ psrc, const float* __restrict__ pref,
        const float* __restrict__ beta, const float* __restrict__ alpha,
        float* __restrict__ ws, float* __restrict__ outT, float* __restrict__ perm)
{
    __shared__ float refL[NPTS * 7];          // 28 KB
    __shared__ float svp[NWAVES][NPTS];       // 32 KB
    __shared__ float wvS[NPTS];               // 4 KB
    __shared__ float sred[NWAVES][16];
    __shared__ float tT[12];
    __shared__ float tTn[12];

    const int blk = blockIdx.x, b = blk & 15, sub = blk >> 4;
    const int tid = threadIdx.x, wid = tid >> 6, lane = tid & 63;
    const int rbase = (sub << 6) + (wid << 3);                  // 64 rows/block
    const int grow  = (b << 10) + rbase;

    float*              accA = ws + WS_ACC;
    unsigned*           bar  = (unsigned*)ws + WS_BARU + b * 32;
    unsigned long long* svU  = (unsigned long long*)ws + WS_SVU;
    unsigned            phase = 0;

    const float bet2 = beta[b] * LOG2E;
    const float alp  = alpha[b];
    const float tb2  = 2.f * bet2;

    // ---- stage ref features to LDS (block-local)
    for (int i = tid; i < NPTS; i += BLOCK_T) {
        const float* p = pref + ((size_t)(b << 10) + i) * 6;
        float x=p[0], y=p[1], z=p[2], aa=p[3], bb=p[4], cc=p[5];
        float* o = refL + i * 7;
        o[0]=x; o[1]=y; o[2]=z; o[3]=aa; o[4]=bb; o[5]=cc;
        o[6] = x*x + y*y + z*z + aa*aa + bb*bb + cc*cc;
    }
    if (tid < 12) tT[tid] = (tid == 0 || tid == 5 || tid == 10) ? 1.f : 0.f;
    __syncthreads();

    // Kh[r][j] holds ADJACENT columns (2*lane + 128*j, +1) packed fp16x2.
    __half2 Kh[8][8];
    float wu[8];

    for (int it = 0; it < REG_ITERS; ++it) {
        const bool last = (it == REG_ITERS - 1);

        // ---- A) K-build
        {
            float rx[8], ry[8], rz[8], f3[8], f4[8], f5[8], cr[8];
            #pragma unroll
            for (int r = 0; r < 8; ++r) {
                const float* p = psrc + (size_t)(grow + r) * 6;
                float x = p[0], y = p[1], z = p[2];
                float tx = tT[0]*x + tT[1]*y + tT[2]*z  + tT[3];
                float ty = tT[4]*x + tT[5]*y + tT[6]*z  + tT[7];
                float tz = tT[8]*x + tT[9]*y + tT[10]*z + tT[11];
                f3[r] = p[3]; f4[r] = p[4]; f5[r] = p[5];
                rx[r] = tx; ry[r] = ty; rz[r] = tz;
                float sq = tx*tx + ty*ty + tz*tz + f3[r]*f3[r] + f4[r]*f4[r] + f5[r]*f5[r];
                cr[r] = bet2 * (alp - sq);
            }
            #pragma unroll
            for (int j = 0; j < 8; ++j) {
                const float* L0 = refL + (2*lane + 128*j) * 7;
                const float* L1 = L0 + 7;
                float a0=L0[0], a1=L0[1], a2=L0[2], a3=L0[3], a4=L0[4], a5=L0[5];
                float c0=L1[0], c1=L1[1], c2=L1[2], c3=L1[3], c4=L1[4], c5=L1[5];
                float tk0 = bet2 * L0[6], tk1 = bet2 * L1[6];
                #pragma unroll
                for (int r = 0; r < 8; ++r) {
                    float d0 = rx[r]*a0 + ry[r]*a1 + rz[r]*a2 + f3[r]*a3 + f4[r]*a4 + f5[r]*a5;
                    float d1 = rx[r]*c0 + ry[r]*c1 + rz[r]*c2 + f3[r]*c3 + f4[r]*c4 + f5[r]*c5;
                    float k0 = __builtin_amdgcn_exp2f(fmaf(tb2, d0, cr[r] - tk0));
                    float k1 = __builtin_amdgcn_exp2f(fmaf(tb2, d1, cr[r] - tk1));
                    Kh[r][j] = __floats2half2_rn(k0, k1);
                }
            }
        }

        // ---- B) 5 x (u-pass local, v-pass -> LDS -> slot store -> barrier
        //            -> cooperative 16-slot read-side sum -> wvS)
        for (int sk = 0; sk < SK_ITERS; ++sk) {
            const int q = it * SK_ITERS + sk;          // global sk phase id
            float Su[8];
            #pragma unroll
            for (int r = 0; r < 8; ++r) Su[r] = 0.f;
            if (sk == 0) {
                #pragma unroll
                for (int j = 0; j < 8; ++j)
                    #pragma unroll
                    for (int r = 0; r < 8; ++r) {
                        float2 kk = __half22float2(Kh[r][j]);
                        Su[r] += kk.x + kk.y;
                    }
            } else {
                float wv0[8], wv1[8];
                #pragma unroll
                for (int j = 0; j < 8; ++j) {
                    wv0[j] = wvS[2*lane + 128*j];
                    wv1[j] = wvS[2*lane + 128*j + 1];
                }
                #pragma unroll
                for (int j = 0; j < 8; ++j)
                    #pragma unroll
                    for (int r = 0; r < 8; ++r) {
                        float2 kk = __half22float2(Kh[r][j]);
                        Su[r] = fmaf(kk.x, wv0[j], fmaf(kk.y, wv1[j], Su[r]));
                    }
            }
            #pragma unroll
            for (int r = 0; r < 8; ++r) {
                float a = Su[r];
                for (int off = 32; off; off >>= 1) a += __shfl_down(a, off);
                wu[r] = __builtin_amdgcn_rcpf(1.f + __shfl(a, 0));
            }
            // v-pass: per-wave column partials -> LDS
            #pragma unroll
            for (int j = 0; j < 8; ++j) {
                float p0 = 0.f, p1 = 0.f;
                #pragma unroll
                for (int r = 0; r < 8; ++r) {
                    float2 kk = __half22float2(Kh[r][j]);
                    p0 = fmaf(kk.x, wu[r], p0);
                    p1 = fmaf(kk.y, wu[r], p1);
                }
                svp[wid][2*lane + 128*j]     = p0;
                svp[wid][2*lane + 128*j + 1] = p1;
            }
            __syncthreads();
            // cross-wave reduce -> ONE private-slot 8B store per thread (no RMW)
            {
                float s0 = 0.f, s1 = 0.f;
                #pragma unroll
                for (int w = 0; w < NWAVES; ++w) {
                    s0 += svp[w][2*tid];
                    s1 += svp[w][2*tid + 1];
                }
                union { float2 f; unsigned long long u; } cv;
                cv.f = make_float2(s0, s1);
                unsigned long long* vb = svU
                    + ((size_t)(((q & 1) * BATCH + b) * BLK_PER_B + sub)) * SLOT_U + tid;
                st_coh64(vb, cv.u);
            }
            batch_barrier(bar, (unsigned)BLK_PER_B * (++phase));
            // cooperative read-side sum of all 16 slots (independent loads,
            // one latency exposure, fixed order -> deterministic)
            {
                const unsigned long long* sb = svU
                    + ((size_t)((q & 1) * BATCH + b) * BLK_PER_B) * SLOT_U + tid;
                unsigned long long g[BLK_PER_B];
                #pragma unroll
                for (int s2 = 0; s2 < BLK_PER_B; ++s2)
                    g[s2] = ld_coh64(sb + s2 * SLOT_U);
                float a0 = 0.f, a1 = 0.f;
                #pragma unroll
                for (int s2 = 0; s2 < BLK_PER_B; ++s2) {
                    union { unsigned long long u; float2 f; } cv; cv.u = g[s2];
                    a0 += cv.f.x; a1 += cv.f.y;
                }
                wvS[2*tid]     = __builtin_amdgcn_rcpf(1.f + a0);
                wvS[2*tid + 1] = __builtin_amdgcn_rcpf(1.f + a1);
            }
            __syncthreads();
        }

        // ---- C) finalize: perm (last iter) + moment accumulators
        //      (wvS already holds rcp(1+Sv) of the last sk phase — no reload)
        {
            float wv0[8], wv1[8];
            #pragma unroll
            for (int j = 0; j < 8; ++j) {
                wv0[j] = wvS[2*lane + 128*j];
                wv1[j] = wvS[2*lane + 128*j + 1];
            }
            float rx[8], ry[8], rz[8];
            #pragma unroll
            for (int r = 0; r < 8; ++r) {
                const float* p = psrc + (size_t)(grow + r) * 6;
                float x = p[0], y = p[1], z = p[2];
                rx[r] = tT[0]*x + tT[1]*y + tT[2]*z  + tT[3];
                ry[r] = tT[4]*x + tT[5]*y + tT[6]*z  + tT[7];
                rz[r] = tT[8]*x + tT[9]*y + tT[10]*z + tT[11];
            }
            float pS[16];
            #pragma unroll
            for (int i2 = 0; i2 < 16; ++i2) pS[i2] = 0.f;
            for (int r = 0; r < 8; ++r) {
                float s=0.f, smx=0.f, smy=0.f, smz=0.f;
                const float w = wu[r];
                #pragma unroll
                for (int j = 0; j < 8; ++j) {
                    int k0 = 2*lane + 128*j;
                    float2 kk = __half22float2(Kh[r][j]);
                    float p0 = kk.x * w * wv0[j];
                    float p1 = kk.y * w * wv1[j];
                    const float* L0 = refL + k0 * 7;
                    const float* L1 = L0 + 7;
                    s += p0 + p1;
                    smx += p0*L0[0] + p1*L1[0];
                    smy += p0*L0[1] + p1*L1[1];
                    smz += p0*L0[2] + p1*L1[2];
                    if (last) {
                        __builtin_nontemporal_store(p0, &perm[(size_t)(grow + r) * NPTS + k0]);
                        __builtin_nontemporal_store(p1, &perm[(size_t)(grow + r) * NPTS + k0 + 1]);
                    }
                }
                for (int off = 32; off; off >>= 1) {
                    s   += __shfl_down(s,   off);
                    smx += __shfl_down(smx, off);
                    smy += __shfl_down(smy, off);
                    smz += __shfl_down(smz, off);
                }
                if (lane == 0) {
                    float inv = 1.f / (s + EPS);
                    float bx = smx*inv, by = smy*inv, bz = smz*inv;
                    float fx = rx[r], fy = ry[r], fz = rz[r];
                    pS[0] += s;
                    pS[1] += s*fx;  pS[2] += s*fy;  pS[3] += s*fz;
                    pS[4] += s*bx;  pS[5] += s*by;  pS[6] += s*bz;
                    pS[7] += s*fx*bx;  pS[8]  += s*fx*by;  pS[9]  += s*fx*bz;
                    pS[10]+= s*fy*bx;  pS[11] += s*fy*by;  pS[12] += s*fy*bz;
                    pS[13]+= s*fz*bx;  pS[14] += s*fz*by;  pS[15] += s*fz*bz;
                }
            }
            if (lane == 0) {
                #pragma unroll
                for (int i2 = 0; i2 < 16; ++i2) sred[wid][i2] = pS[i2];
            }
            __syncthreads();
            float* ac = accA + it * 256 + b * 16;
            if (tid < 16) {
                float s = sred[0][tid] + sred[1][tid] + sred[2][tid] + sred[3][tid]
                        + sred[4][tid] + sred[5][tid] + sred[6][tid] + sred[7][tid];
                add_coh(&ac[tid], s);
            }
            batch_barrier(bar, (unsigned)BLK_PER_B * (++phase));

            // ---- D) SVD redundantly per block from identical accum bits
            if (!last || sub == 0) {
                if (tid == 0) {
                    float acl[16];
                    #pragma unroll
                    for (int i2 = 0; i2 < 16; ++i2) acl[i2] = ld_coh(&ac[i2]);
                    float Tl[12];
                    #pragma unroll
                    for (int i2 = 0; i2 < 12; ++i2) Tl[i2] = tT[i2];
                    kabsch_svd(acl, Tl, tTn);
                }
                __syncthreads();
                if (tid < 12) tT[tid] = tTn[tid];
                __syncthreads();
                if (last && tid == 0) {
                    #pragma unroll
                    for (int i2 = 0; i2 < 12; ++i2) outT[b * 12 + i2] = tT[i2];
                }
            }
        }
    }
}

extern "C" void kernel_launch(void* const* d_in, const int* in_sizes, int n_in,
                              void* d_out, int out_size, void* d_ws, size_t ws_size,
                              hipStream_t stream) {
    const float* psrc  = (const float*)d_in[0];
    const float* pref  = (const float*)d_in[1];
    const float* beta  = (const float*)d_in[2];
    const float* alpha = (const float*)d_in[3];

    float* out     = (float*)d_out;
    float* outT    = out;            // (16,3,4)
    float* outPerm = out + 192;      // (16,1024,1024)
    float* ws      = (float*)d_ws;

    prep_kernel<<<PREP_FLOATS / 256, 256, 0, stream>>>(ws);

    void* args[] = { (void*)&psrc, (void*)&pref, (void*)&beta, (void*)&alpha,
                     (void*)&ws, (void*)&outT, (void*)&outPerm };
    hipError_t ce = hipLaunchCooperativeKernel((const void*)rpm_kernel,
                                               dim3(BATCH * BLK_PER_B), dim3(BLOCK_T),
                                               args, 0, stream);
    if (ce != hipSuccess) {
        rpm_kernel<<<dim3(BATCH * BLK_PER_B), dim3(BLOCK_T), 0, stream>>>(
            psrc, pref, beta, alpha, ws, outT, outPerm);
    }
}